// Round 14
// baseline (108.506 us; speedup 1.0000x reference)
//
#include <hip/hip_runtime.h>
#include <hip/hip_bf16.h>

typedef __bf16 bf16x8 __attribute__((ext_vector_type(8)));
typedef float f32x4 __attribute__((ext_vector_type(4)));

constexpr int NE   = 16;
constexpr int NB   = 4096;
constexpr int INF  = 1024;
constexpr int OUTF = 1024;
constexpr int BM = 64, BN = 128, BK = 32;
constexpr int NSTEP  = INF / BK;    // 32 steps per K-half (split-K=2)
constexpr int ABYTES = BM * BK * 4; //  8 KiB A f32 tile
constexpr int BBYTES = BN * BK * 4; // 16 KiB B f32 tile
constexpr int MAXMT  = NB / BM;     // 64 worst-case M-tiles per expert

// f32x4 pair -> bf16x8 (RTNE scalar casts; compiler fuses to v_cvt_pk_bf16_f32)
__device__ __forceinline__ bf16x8 cvt8(const f32x4 lo, const f32x4 hi) {
  bf16x8 r;
  r[0] = (__bf16)lo[0]; r[1] = (__bf16)lo[1];
  r[2] = (__bf16)lo[2]; r[3] = (__bf16)lo[3];
  r[4] = (__bf16)hi[0]; r[5] = (__bf16)hi[1];
  r[6] = (__bf16)hi[2]; r[7] = (__bf16)hi[3];
  return r;
}

// async global->LDS DMA, 16 B per lane. Dest is wave-uniform base; HW writes
// lane i at base + i*16. Source is per-lane (gather + pre-swizzle legal).
__device__ __forceinline__ void glds16(const float* g, char* l) {
  __builtin_amdgcn_global_load_lds(
      (const __attribute__((address_space(1))) void*)g,
      (__attribute__((address_space(3))) void*)l, 16, 0, 0);
}

__global__ void route_init_kernel(int* counts) {
  if (threadIdx.x < NE) counts[threadIdx.x] = 0;
}

__global__ void route_kernel(const int* __restrict__ eidx, int* counts, int* rows) {
  int i = blockIdx.x * blockDim.x + threadIdx.x;
  if (i < NB) {
    int e = eidx[i];
    int slot = atomicAdd(&counts[e], 1);
    rows[e * NB + slot] = i;
  }
}

// grid: (OUTF/BN, MAXMT, NE*2), z = expert*2 + khalf. khalf=0: logits·W0
// (+bias), khalf=1: prior·W1. Exactly two commutative f32 atomicAdds per
// output element on a zeroed base => deterministic.
//
// K-loop sync (T4, counted vmcnt — NEVER drain to 0 mid-loop):
//   iter s: s_waitcnt vmcnt(6)   <- waits buffer-s loads; 6 newer in flight
//           s_barrier
//           compute(buf[s&1])
//           s_barrier
//           stage(buf[s&1], s+2) <- overwrites only after all waves read it
__global__ __launch_bounds__(256, 3) void ens_gemm_kernel(
    const float* __restrict__ X0,    // logits     [NB, INF]
    const float* __restrict__ X1,    // prior      [NB, INF]
    const float* __restrict__ W0,    // [NE, OUTF, INF]
    const float* __restrict__ B0,    // [NE, OUTF]
    const float* __restrict__ W1,
    const float* __restrict__ B1,
    const int* __restrict__ counts,
    const int* __restrict__ rows,
    const float* __restrict__ zrow,  // 4 KiB of zeros (dead-row source)
    float* __restrict__ out)         // [NB, OUTF] (pre-zeroed)
{
  const int e  = blockIdx.z >> 1;
  const int kh = blockIdx.z & 1;
  const int mt = blockIdx.y;
  const int n0 = blockIdx.x * BN;
  const int me = counts[e];
  const int m0 = mt * BM;
  if (m0 >= me) return;              // dead tile — cheap early exit

  __shared__ __align__(16) char smem[2 * (ABYTES + BBYTES)]; // dbuf A+B (48 KiB)
  __shared__ int rid[BM];

  const int t = threadIdx.x;
  if (t < BM) rid[t] = (m0 + t < me) ? rows[e * NB + m0 + t] : -1;
  __syncthreads();

  const int w  = t >> 6;
  const int l  = t & 63;
  const int lr = l & 15;
  const int lk = l >> 4;
  const int wm = (w >> 1) * 32;     // wave M origin (2 waves in M)
  const int wn = (w & 1) * 64;      // wave N origin (2 waves in N)

  const float* xs  = kh ? X1 : X0;
  const float* wsp = (kh ? W1 : W0) + (size_t)e * OUTF * INF;

  // Staging: each 1 KiB LDS chunk = 8 rows x 128 B (one K=32 f32 slice).
  // Lane l covers row (l>>3), swizzled 16B-slot (l&7): source float offset
  // 4*((l&7) ^ ((l>>3)&7)).  (linear dest + inverse-swizzled source)
  const int sub = l >> 3;
  const int swz = 4 * ((l & 7) ^ (sub & 7));

  const int ar0 = (2 * w) * 8 + sub;       // A rows this wave stages
  const int ar1 = (2 * w + 1) * 8 + sub;
  const int r0 = rid[ar0], r1 = rid[ar1];
  const float* pa0 = ((r0 >= 0) ? xs + (size_t)r0 * INF : zrow) + swz;
  const float* pa1 = ((r1 >= 0) ? xs + (size_t)r1 * INF : zrow) + swz;
  const float* pb0 = wsp + (size_t)(n0 + (4 * w)     * 8 + sub) * INF + swz;
  const float* pb1 = wsp + (size_t)(n0 + (4 * w + 1) * 8 + sub) * INF + swz;
  const float* pb2 = wsp + (size_t)(n0 + (4 * w + 2) * 8 + sub) * INF + swz;
  const float* pb3 = wsp + (size_t)(n0 + (4 * w + 3) * 8 + sub) * INF + swz;

  f32x4 acc[2][4] = {};

  auto stage = [&](char* base, int s) {
    char* ab = base;
    char* bb = base + ABYTES;
    const int o = s * BK;            // float offset of this K-slice
    glds16(pa0 + o, ab + (2 * w) * 1024);
    glds16(pa1 + o, ab + (2 * w + 1) * 1024);
    glds16(pb0 + o, bb + (4 * w) * 1024);
    glds16(pb1 + o, bb + (4 * w + 1) * 1024);
    glds16(pb2 + o, bb + (4 * w + 2) * 1024);
    glds16(pb3 + o, bb + (4 * w + 3) * 1024);
  };

  auto compute = [&](const char* base) {
    const char* ab = base;
    const char* bb = base + ABYTES;
    bf16x8 af[2], bv[4];
#pragma unroll
    for (int f = 0; f < 2; ++f) {
      const int row = wm + f * 16 + lr;
      const int c0 = (lk * 32) ^ ((row & 7) << 4);   // swizzled byte col
      f32x4 lo = *(const f32x4*)(ab + row * 128 + c0);
      f32x4 hi = *(const f32x4*)(ab + row * 128 + (c0 ^ 16));
      af[f] = cvt8(lo, hi);
    }
#pragma unroll
    for (int f = 0; f < 4; ++f) {
      const int row = wn + f * 16 + lr;
      const int c0 = (lk * 32) ^ ((row & 7) << 4);
      f32x4 lo = *(const f32x4*)(bb + row * 128 + c0);
      f32x4 hi = *(const f32x4*)(bb + row * 128 + (c0 ^ 16));
      bv[f] = cvt8(lo, hi);
    }
#pragma unroll
    for (int fm = 0; fm < 2; ++fm)
#pragma unroll
      for (int fn = 0; fn < 4; ++fn)
        acc[fm][fn] = __builtin_amdgcn_mfma_f32_16x16x32_bf16(
            af[fm], bv[fn], acc[fm][fn], 0, 0, 0);
  };

  char* b0 = smem;
  char* b1 = smem + (ABYTES + BBYTES);

  // prologue: two stages in flight (12 outstanding loads per wave)
  stage(b0, 0);
  stage(b1, 1);

  for (int s = 0; s < NSTEP; ++s) {
    if (s < NSTEP - 1) {
      asm volatile("s_waitcnt vmcnt(6)" ::: "memory");   // cur landed; 6 newer in flight
    } else {
      asm volatile("s_waitcnt vmcnt(0)" ::: "memory");   // tail: nothing newer
    }
    __builtin_amdgcn_sched_barrier(0);
    __builtin_amdgcn_s_barrier();            // raw barrier — no implicit drain
    compute((s & 1) ? b1 : b0);              // ds_read + cvt + MFMA
    __builtin_amdgcn_s_barrier();            // all waves done reading buffer
    if (s + 2 < NSTEP) stage((s & 1) ? b1 : b0, s + 2);  // refill, fire-and-forget
  }

  // epilogue: atomic accumulate (exactly 2 adds per element, commutative)
  const float* Bb0 = B0 + e * OUTF;
  const float* Bb1 = B1 + e * OUTF;
#pragma unroll
  for (int fn = 0; fn < 4; ++fn) {
    const int gcol = n0 + wn + fn * 16 + lr;
    const float bias = (kh == 0) ? (Bb0[gcol] + Bb1[gcol]) : 0.f;
#pragma unroll
    for (int fm = 0; fm < 2; ++fm) {
#pragma unroll
      for (int j = 0; j < 4; ++j) {
        const int sl = wm + fm * 16 + lk * 4 + j;   // slot in tile
        const int r = rid[sl];
        if (r >= 0) atomicAdd(&out[(size_t)r * OUTF + gcol], acc[fm][fn][j] + bias);
      }
    }
  }
}

extern "C" void kernel_launch(void* const* d_in, const int* in_sizes, int n_in,
                              void* d_out, int out_size, void* d_ws, size_t ws_size,
                              hipStream_t stream) {
  const float* logits = (const float*)d_in[0];
  const float* prior  = (const float*)d_in[1];
  const float* W      = (const float*)d_in[2];
  const float* b      = (const float*)d_in[3];
  const float* Wp     = (const float*)d_in[4];
  const float* bp     = (const float*)d_in[5];
  const int*   eidx   = (const int*)d_in[6];
  float* out = (float*)d_out;

  int* counts = (int*)d_ws;
  int* rows   = counts + 32;                 // NE*NB ints
  float* zrow = (float*)(rows + NE * NB);    // 4 KiB zero page

  // split-K accumulates via atomics — output must start at exactly 0.f
  (void)hipMemsetAsync(d_out, 0, (size_t)out_size * sizeof(float), stream);
  (void)hipMemsetAsync(zrow, 0, 4096, stream);

  hipLaunchKernelGGL(route_init_kernel, dim3(1), dim3(64), 0, stream, counts);
  hipLaunchKernelGGL(route_kernel, dim3(NB / 256), dim3(256), 0, stream,
                     eidx, counts, rows);

  dim3 grid(OUTF / BN, MAXMT, NE * 2);
  hipLaunchKernelGGL(ens_gemm_kernel, grid, dim3(256), 0, stream,
                     logits, prior, W, b, Wp, bp, counts, rows, zrow, out);
}